// Round 1
// 502.336 us; speedup vs baseline: 1.0704x; 1.0704x over previous
//
#include <hip/hip_runtime.h>
#include <math.h>

// CTC loss (warp-ctc 'mean' reduction) on MI355X.
// Phase 1: per-(t,b) log-softmax denom + gather extended-label probs
//          p_ext[b][t][s] = exp(act[t,b,ext[s]] - lse), stride 256, pad 0.
// Phase 2: linear-space alpha recursion, 1 wave/utterance, 4 states/lane,
//          2 DP steps per lane-exchange (halo recompute). Renormalize every
//          4 steps to max ~ 2^64 (biased target keeps transient dips far from
//          the fp32 flush-to-zero floor; integer exponent accumulator E).
//          __launch_bounds__(64,1) so the PF=8 prefetch pipeline (96 VGPRs of
//          float4 buffers) actually lives in registers; DPP wave_shr:1 halo.
// Phase 3: double-precision reduction to the scalar.

#define BLK 256

__global__ __launch_bounds__(BLK) void k_lse_gather(
    const float* __restrict__ act, const int* __restrict__ targets,
    float* __restrict__ p_ext, int T, int B, int C, int L, int S)
{
  int row = blockIdx.x;            // row = t*B + b  (act is [T,B,C])
  int b = row % B;
  int t = row / B;
  int tid = threadIdx.x;
  const float* rp = act + (size_t)row * (size_t)C;
  const float4* rp4 = (const float4*)rp;
  int C4 = C >> 2;                 // 500 for C=2000

  // pass A: max. Two statically-addressed register chunks (C4 <= 2*BLK here);
  // generic overflow loop kept for safety (never taken at C=2000).
  float4 x0 = (tid < C4) ? rp4[tid] : make_float4(-3e38f, -3e38f, -3e38f, -3e38f);
  bool h2 = (tid + BLK) < C4;
  float4 x1 = h2 ? rp4[tid + BLK] : make_float4(0.f, 0.f, 0.f, 0.f);
  float m = fmaxf(fmaxf(x0.x, x0.y), fmaxf(x0.z, x0.w));
  if (h2) m = fmaxf(m, fmaxf(fmaxf(x1.x, x1.y), fmaxf(x1.z, x1.w)));
  for (int i = tid + 2 * BLK; i < C4; i += BLK) {
    float4 x = rp4[i];
    m = fmaxf(m, fmaxf(fmaxf(x.x, x.y), fmaxf(x.z, x.w)));
  }
  #pragma unroll
  for (int o = 32; o > 0; o >>= 1) m = fmaxf(m, __shfl_xor(m, o));
  __shared__ float sm[BLK / 64];
  __shared__ float ss[BLK / 64];
  int w = tid >> 6, ln = tid & 63;
  if (ln == 0) sm[w] = m;
  __syncthreads();
  float M = fmaxf(fmaxf(sm[0], sm[1]), fmaxf(sm[2], sm[3]));

  // pass B: sum exp(x - M) from registers
  float ssum = 0.f;
  if (tid < C4)
    ssum += expf(x0.x - M) + expf(x0.y - M) + expf(x0.z - M) + expf(x0.w - M);
  if (h2)
    ssum += expf(x1.x - M) + expf(x1.y - M) + expf(x1.z - M) + expf(x1.w - M);
  for (int i = tid + 2 * BLK; i < C4; i += BLK) {
    float4 x = rp4[i];
    ssum += expf(x.x - M) + expf(x.y - M) + expf(x.z - M) + expf(x.w - M);
  }
  #pragma unroll
  for (int o = 32; o > 0; o >>= 1) ssum += __shfl_xor(ssum, o);
  if (ln == 0) ss[w] = ssum;
  __syncthreads();
  float lse = M + logf(ss[0] + ss[1] + ss[2] + ss[3]);

  // gather; pad slots [S,256) with 0 so invalid DP states stay exactly 0.
  float* op = p_ext + ((size_t)b * T + t) * 256;
  float p = 0.f;
  if (tid < S) {
    int c = (tid & 1) ? targets[b * L + (tid >> 1)] : 0;   // blank == 0
    p = expf(rp[c] - lse);
  }
  op[tid] = p;
}

// 64-lane max reduction, pure DPP (no DS latency); returns uniform value.
// All inputs are >= 0 (alphas), so bound_ctrl-zeros are harmless under max.
__device__ __forceinline__ float wave_max64(float x) {
  int t;
  t = __builtin_amdgcn_update_dpp(0, __float_as_int(x), 0x111, 0xF, 0xF, true);  // row_shr:1
  x = fmaxf(x, __int_as_float(t));
  t = __builtin_amdgcn_update_dpp(0, __float_as_int(x), 0x112, 0xF, 0xF, true);  // row_shr:2
  x = fmaxf(x, __int_as_float(t));
  t = __builtin_amdgcn_update_dpp(0, __float_as_int(x), 0x114, 0xF, 0xF, true);  // row_shr:4
  x = fmaxf(x, __int_as_float(t));
  t = __builtin_amdgcn_update_dpp(0, __float_as_int(x), 0x118, 0xF, 0xF, true);  // row_shr:8
  x = fmaxf(x, __int_as_float(t));
  t = __builtin_amdgcn_update_dpp(0, __float_as_int(x), 0x142, 0xA, 0xF, false); // row_bcast:15
  x = fmaxf(x, __int_as_float(t));
  t = __builtin_amdgcn_update_dpp(0, __float_as_int(x), 0x143, 0xC, 0xF, false); // row_bcast:31
  x = fmaxf(x, __int_as_float(t));
  return __int_as_float(__builtin_amdgcn_readlane(__float_as_int(x), 63));
}

// lane i <- lane i-1, lane 0 <- 0.  DPP wave_shr:1 with bound_ctrl zero-fill.
// Replaces __shfl_up (ds_bpermute + lgkmcnt wait) with a 1-VALU-op shift.
__device__ __forceinline__ float shift_up1(float x) {
  int t = __builtin_amdgcn_update_dpp(0, __float_as_int(x), 0x138, 0xF, 0xF, true); // wave_shr:1
  return __int_as_float(t);
}

__global__ __launch_bounds__(64, 1) void k_alpha(
    const float* __restrict__ p_ext, const int* __restrict__ targets,
    const int* __restrict__ ilen, const int* __restrict__ tlen,
    double* __restrict__ costs, int T, int B, int L)
{
  int b = blockIdx.x;
  int l = threadIdx.x;              // lane owns states 4l..4l+3
  int Tb = ilen[b];
  int Lb = tlen[b];
  int S = 2 * Lb + 1;

  const float4* pb4 = (const float4*)(p_ext + (size_t)b * (size_t)T * 256);

  // skip flags (0/1 floats) for the odd states this lane updates:
  // kf3 -> state 4l-1 (halo recompute), kf5 -> 4l+1, kf7 -> 4l+3.
  const int* tg = targets + b * L;
  float kf3 = 0.f, kf5 = 0.f, kf7 = 0.f;
  {
    int s;
    s = 4 * l - 1; if (s >= 3 && s < S) { int mm = (s - 1) >> 1; kf3 = (tg[mm] != tg[mm - 1]) ? 1.f : 0.f; }
    s = 4 * l + 1; if (s >= 3 && s < S) { int mm = (s - 1) >> 1; kf5 = (tg[mm] != tg[mm - 1]) ? 1.f : 0.f; }
    s = 4 * l + 3; if (s >= 3 && s < S) { int mm = (s - 1) >> 1; kf7 = (tg[mm] != tg[mm - 1]) ? 1.f : 0.f; }
  }

  // t = 0 init, pre-biased to 2^64 (true alpha = stored * 2^E).
  const float BIAS = 18446744073709551616.0f;   // 2^64
  float a0 = 0.f, a1 = 0.f, a2 = 0.f, a3 = 0.f;
  {
    float4 p0 = pb4[l];
    if (l == 0) { a0 = p0.x * BIAS; a1 = p0.y * BIAS; }
  }
  int E = -64;

  int i0 = (l == 0) ? 0 : (l - 1); // halo float4 index (lane0 halo is 0 anyway)

  const int PF = 8;                 // prefetch depth in exchanges (16 steps)
  int NE = (Tb - 1) >> 1;           // full 2-step exchanges
  int tmax = T - 2;                 // uniform row clamp: rows [0,T-1] exist for
                                    // every b, so over-prefetch reads valid
                                    // (never-consumed) data instead of branching.
  float4 fa[PF], fb[PF], fc[PF];    // halo@t, own@t, own@t+1
  #pragma unroll
  for (int j = 0; j < PF; j++) {
    int t0 = 1 + 2 * j;
    t0 = (t0 > tmax) ? tmax : t0;
    fa[j] = pb4[(size_t)t0 * 64 + i0];
    fb[j] = pb4[(size_t)t0 * 64 + l];
    fc[j] = pb4[(size_t)(t0 + 1) * 64 + l];
  }

  int e = 0;
  while (e < NE) {
    #pragma unroll
    for (int j = 0; j < PF; j++) {
      int eg = e + j;
      if (eg < NE) {                // wave-uniform
        float4 Pa = fa[j], Pb = fb[j], Pc = fc[j];
        {
          int tn = 1 + 2 * (eg + PF);
          tn = (tn > tmax) ? tmax : tn;   // unconditional clamped prefetch
          fa[j] = pb4[(size_t)tn * 64 + i0];
          fb[j] = pb4[(size_t)tn * 64 + l];
          fc[j] = pb4[(size_t)(tn + 1) * 64 + l];
        }

        // halo: w0..w3 = prev lane's a0..a3 (DPP wave_shr:1, lane0 -> 0)
        float w0 = shift_up1(a0), w1 = shift_up1(a1);
        float w2 = shift_up1(a2), w3 = shift_up1(a3);
        float w4 = a0, w5 = a1, w6 = a2, w7 = a3;

        // step 1 (time t): in-place descending update of window i=7..2
        w7 = (w7 + w6 + kf7 * w5) * Pb.w;
        w6 = (w6 + w5) * Pb.z;
        w5 = (w5 + w4 + kf5 * w3) * Pb.y;
        w4 = (w4 + w3) * Pb.x;
        w3 = (w3 + w2 + kf3 * w1) * Pa.w;
        w2 = (w2 + w1) * Pa.z;
        // step 2 (time t+1): own states only
        w7 = (w7 + w6 + kf7 * w5) * Pc.w;
        w6 = (w6 + w5) * Pc.z;
        w5 = (w5 + w4 + kf5 * w3) * Pc.y;
        w4 = (w4 + w3) * Pc.x;
        a0 = w4; a1 = w5; a2 = w6; a3 = w7;

        if ((j & 1) == 1) {          // renorm every 2 exchanges = 4 steps
          float mx = fmaxf(fmaxf(a0, a1), fmaxf(a2, a3));
          float Mx = wave_max64(mx);
          // rescale so max lands in [2^64, 2^65): exact power-of-2 scaling.
          int ee = ilogbf(fmaxf(Mx, 1.17549435e-38f)) - 64;
          float sc = ldexpf(1.0f, -ee);
          a0 *= sc; a1 *= sc; a2 *= sc; a3 *= sc;
          E += ee;
        }
      }
    }
    e += PF;
  }

  // tail: at most one leftover single step
  int t = 1 + 2 * NE;
  if (t < Tb) {
    float4 P = pb4[(size_t)t * 64 + l];
    float u3 = shift_up1(a3);
    float n0 = (a0 + u3) * P.x;
    float n1 = (a1 + a0 + kf5 * u3) * P.y;
    float n2 = (a2 + a1) * P.z;
    float n3 = (a3 + a2 + kf7 * a1) * P.w;
    a0 = n0; a1 = n1; a2 = n2; a3 = n3;
  }

  __shared__ float sA[260];
  sA[4 * l + 0] = a0; sA[4 * l + 1] = a1;
  sA[4 * l + 2] = a2; sA[4 * l + 3] = a3;
  __syncthreads();
  if (l == 0) {
    double ab = (double)sA[2 * Lb];       // final blank state
    double al_ = (double)sA[2 * Lb - 1];  // final label state
    costs[b] = -(log(ab + al_) + (double)E * 0.6931471805599453);
  }
}

__global__ __launch_bounds__(64) void k_final(
    const double* __restrict__ costs, const int* __restrict__ tlen,
    float* __restrict__ out, int B)
{
  int i = threadIdx.x;
  double c = (i < B) ? costs[i] : 0.0;
  double tl = (i < B) ? (double)tlen[i] : 0.0;
  #pragma unroll
  for (int o = 32; o > 0; o >>= 1) {
    c += __shfl_xor(c, o);
    tl += __shfl_xor(tl, o);
  }
  if (i == 0) out[0] = (float)(c / (double)B / tl);
}

extern "C" void kernel_launch(void* const* d_in, const int* in_sizes, int n_in,
                              void* d_out, int out_size, void* d_ws, size_t ws_size,
                              hipStream_t stream) {
  const float* act     = (const float*)d_in[0];   // [T,B,C] fp32
  const int*   targets = (const int*)d_in[1];     // [B*L]
  const int*   ilen    = (const int*)d_in[2];     // [B]
  const int*   tlen    = (const int*)d_in[3];     // [B]
  float* out = (float*)d_out;

  int B = in_sizes[2];
  int L = in_sizes[1] / B;
  const int T = 1000, C = 2000;     // fixed by the problem (in_sizes[0] = T*B*C)
  int S = 2 * L + 1;                // 201 <= 256

  float* p_ext = (float*)d_ws;                           // B*T*256 floats (~32.8 MB)
  double* costs = (double*)(p_ext + (size_t)B * T * 256); // B doubles (8B-aligned)

  k_lse_gather<<<T * B, BLK, 0, stream>>>(act, targets, p_ext, T, B, C, L, S);
  k_alpha<<<B, 64, 0, stream>>>(p_ext, targets, ilen, tlen, costs, T, B, L);
  k_final<<<1, 64, 0, stream>>>(costs, tlen, out, B);
}

// Round 3
// 476.508 us; speedup vs baseline: 1.1284x; 1.0542x over previous
//
#include <hip/hip_runtime.h>
#include <math.h>

// CTC loss (warp-ctc 'mean' reduction) on MI355X.
// Phase 1: per-(t,b) log-softmax denom + gather extended-label probs
//          p_ext[b][t][s] = exp(act[t,b,ext[s]] - lse), stride 256, pad 0.
// Phase 2: linear-space alpha recursion, 1 wave/utterance, 4 states/lane,
//          2 DP steps per exchange. Memory pipeline via global_load_lds
//          into a 50-row x 1KB LDS ring (48 loads in flight, counted
//          s_waitcnt vmcnt(44)) — pipeline state lives in LDS, so the
//          register allocator/scheduler cannot sink, rotate, or race it
//          (round-1: source arrays got sunk; round-2: VGPR asm ring faulted).
//          Halo row derived from own row via DPP wave_shr:1.
// Phase 3: double-precision reduction to the scalar.

#define BLK 256
#define RING 50     // LDS ring rows (1 KB each) -> 50 KB
#define AHEAD 48    // rows issued ahead = outstanding global_load_lds

typedef float f32x4 __attribute__((ext_vector_type(4)));

__global__ __launch_bounds__(BLK) void k_lse_gather(
    const float* __restrict__ act, const int* __restrict__ targets,
    float* __restrict__ p_ext, int T, int B, int C, int L, int S)
{
  int row = blockIdx.x;            // row = t*B + b  (act is [T,B,C])
  int b = row % B;
  int t = row / B;
  int tid = threadIdx.x;
  const float* rp = act + (size_t)row * (size_t)C;
  const float4* rp4 = (const float4*)rp;
  int C4 = C >> 2;                 // 500 for C=2000

  // pass A: max. Two statically-addressed register chunks (C4 <= 2*BLK here);
  // generic overflow loop kept for safety (never taken at C=2000).
  float4 x0 = (tid < C4) ? rp4[tid] : make_float4(-3e38f, -3e38f, -3e38f, -3e38f);
  bool h2 = (tid + BLK) < C4;
  float4 x1 = h2 ? rp4[tid + BLK] : make_float4(0.f, 0.f, 0.f, 0.f);
  float m = fmaxf(fmaxf(x0.x, x0.y), fmaxf(x0.z, x0.w));
  if (h2) m = fmaxf(m, fmaxf(fmaxf(x1.x, x1.y), fmaxf(x1.z, x1.w)));
  for (int i = tid + 2 * BLK; i < C4; i += BLK) {
    float4 x = rp4[i];
    m = fmaxf(m, fmaxf(fmaxf(x.x, x.y), fmaxf(x.z, x.w)));
  }
  #pragma unroll
  for (int o = 32; o > 0; o >>= 1) m = fmaxf(m, __shfl_xor(m, o));
  __shared__ float sm[BLK / 64];
  __shared__ float ss[BLK / 64];
  int w = tid >> 6, ln = tid & 63;
  if (ln == 0) sm[w] = m;
  __syncthreads();
  float M = fmaxf(fmaxf(sm[0], sm[1]), fmaxf(sm[2], sm[3]));

  // pass B: sum exp(x - M) from registers
  float ssum = 0.f;
  if (tid < C4)
    ssum += expf(x0.x - M) + expf(x0.y - M) + expf(x0.z - M) + expf(x0.w - M);
  if (h2)
    ssum += expf(x1.x - M) + expf(x1.y - M) + expf(x1.z - M) + expf(x1.w - M);
  for (int i = tid + 2 * BLK; i < C4; i += BLK) {
    float4 x = rp4[i];
    ssum += expf(x.x - M) + expf(x.y - M) + expf(x.z - M) + expf(x.w - M);
  }
  #pragma unroll
  for (int o = 32; o > 0; o >>= 1) ssum += __shfl_xor(ssum, o);
  if (ln == 0) ss[w] = ssum;
  __syncthreads();
  float lse = M + logf(ss[0] + ss[1] + ss[2] + ss[3]);

  // gather; pad slots [S,256) with 0 so invalid DP states stay exactly 0.
  float* op = p_ext + ((size_t)b * T + t) * 256;
  float p = 0.f;
  if (tid < S) {
    int c = (tid & 1) ? targets[b * L + (tid >> 1)] : 0;   // blank == 0
    p = expf(rp[c] - lse);
  }
  op[tid] = p;
}

// 64-lane max reduction, pure DPP (no DS latency); returns uniform value.
// All inputs are >= 0 (alphas), so bound_ctrl-zeros are harmless under max.
__device__ __forceinline__ float wave_max64(float x) {
  int t;
  t = __builtin_amdgcn_update_dpp(0, __float_as_int(x), 0x111, 0xF, 0xF, true);  // row_shr:1
  x = fmaxf(x, __int_as_float(t));
  t = __builtin_amdgcn_update_dpp(0, __float_as_int(x), 0x112, 0xF, 0xF, true);  // row_shr:2
  x = fmaxf(x, __int_as_float(t));
  t = __builtin_amdgcn_update_dpp(0, __float_as_int(x), 0x114, 0xF, 0xF, true);  // row_shr:4
  x = fmaxf(x, __int_as_float(t));
  t = __builtin_amdgcn_update_dpp(0, __float_as_int(x), 0x118, 0xF, 0xF, true);  // row_shr:8
  x = fmaxf(x, __int_as_float(t));
  t = __builtin_amdgcn_update_dpp(0, __float_as_int(x), 0x142, 0xA, 0xF, false); // row_bcast:15
  x = fmaxf(x, __int_as_float(t));
  t = __builtin_amdgcn_update_dpp(0, __float_as_int(x), 0x143, 0xC, 0xF, false); // row_bcast:31
  x = fmaxf(x, __int_as_float(t));
  return __int_as_float(__builtin_amdgcn_readlane(__float_as_int(x), 63));
}

// lane i <- lane i-1, lane 0 <- 0.  DPP wave_shr:1 with bound_ctrl zero-fill.
__device__ __forceinline__ float shift_up1(float x) {
  int t = __builtin_amdgcn_update_dpp(0, __float_as_int(x), 0x138, 0xF, 0xF, true); // wave_shr:1
  return __int_as_float(t);
}

// async global -> LDS, 16 B per lane. LDS dest = uniform base + lane*16.
__device__ __forceinline__ void gload_lds16(const float* g, float* l) {
  __builtin_amdgcn_global_load_lds(
      (const __attribute__((address_space(1))) void*)(const void*)g,
      (__attribute__((address_space(3))) void*)(void*)l, 16, 0, 0);
}

__global__ __launch_bounds__(64, 1) void k_alpha(
    const float* __restrict__ p_ext, const int* __restrict__ targets,
    const int* __restrict__ ilen, const int* __restrict__ tlen,
    double* __restrict__ costs, int T, int B, int L)
{
  __shared__ float ring[RING * 256];   // 50 KB: row t lives at slot (t-1)%RING
  __shared__ float sA[260];

  int b = blockIdx.x;
  int l = threadIdx.x;              // lane owns states 4l..4l+3
  int Tb = ilen[b];
  int Lb = tlen[b];
  int S = 2 * Lb + 1;

  const float* pbase = p_ext + (size_t)b * (size_t)T * 256;
  const float4* pb4 = (const float4*)pbase;

  // skip flags (0/1 floats) for the odd states this lane updates:
  // kf3 -> state 4l-1 (halo recompute), kf5 -> 4l+1, kf7 -> 4l+3.
  const int* tg = targets + b * L;
  float kf3 = 0.f, kf5 = 0.f, kf7 = 0.f;
  {
    int s;
    s = 4 * l - 1; if (s >= 3 && s < S) { int mm = (s - 1) >> 1; kf3 = (tg[mm] != tg[mm - 1]) ? 1.f : 0.f; }
    s = 4 * l + 1; if (s >= 3 && s < S) { int mm = (s - 1) >> 1; kf5 = (tg[mm] != tg[mm - 1]) ? 1.f : 0.f; }
    s = 4 * l + 3; if (s >= 3 && s < S) { int mm = (s - 1) >> 1; kf7 = (tg[mm] != tg[mm - 1]) ? 1.f : 0.f; }
  }

  // t = 0 init, pre-biased to 2^64 (true alpha = stored * 2^E).
  const float BIAS = 18446744073709551616.0f;   // 2^64
  float a0 = 0.f, a1 = 0.f, a2 = 0.f, a3 = 0.f;
  {
    float4 p0 = pb4[l];
    if (l == 0) { a0 = p0.x * BIAS; a1 = p0.y * BIAS; }
  }
  int E = -64;

  int NE = (Tb - 1) >> 1;           // full 2-step exchanges
  int tmax = T - 1;                 // uniform row clamp (rows [0,T-1] valid;
                                    // clamped rows are never consumed)

  // prologue: issue rows 1..AHEAD into slots 0..AHEAD-1 (48 outstanding)
  for (int r = 1; r <= AHEAD; ++r) {
    int tr = (r > tmax) ? tmax : r;
    gload_lds16(pbase + (size_t)tr * 256 + 4 * l, &ring[(r - 1) * 256]);
  }

  // rows 1,2 ready after the oldest 2 complete
  asm volatile("s_waitcnt vmcnt(46)" ::: "memory");
  f32x4 Pb = *(const f32x4*)&ring[0 * 256 + 4 * l];
  f32x4 Pc = *(const f32x4*)&ring[1 * 256 + 4 * l];

  int sr = 2;       // ds_read slot of row 3+2e
  int si = AHEAD;   // issue slot of row 49+2e  == (48+2e)%RING
  for (int e = 0; e < NE; ++e) {
    // loads issued so far = 48+2e; rows 3+2e,4+2e are loads #3+2e,#4+2e
    // -> outstanding <= 44 guarantees them.
    asm volatile("s_waitcnt vmcnt(44)" ::: "memory");
    f32x4 Nb = *(const f32x4*)&ring[sr * 256 + 4 * l];
    f32x4 Nc = *(const f32x4*)&ring[sr * 256 + 256 + 4 * l];
    {
      int t1 = 49 + 2 * e; if (t1 > tmax) t1 = tmax;
      int t2 = 50 + 2 * e; if (t2 > tmax) t2 = tmax;
      gload_lds16(pbase + (size_t)t1 * 256 + 4 * l, &ring[si * 256]);
      gload_lds16(pbase + (size_t)t2 * 256 + 4 * l, &ring[si * 256 + 256]);
    }
    sr += 2; if (sr >= RING) sr = 0;
    si += 2; if (si >= RING) si = 0;

    // halo row values = prev lane's Pb.z/.w (DPP wave_shr:1, lane0 -> 0)
    float paz = shift_up1(Pb.z), paw = shift_up1(Pb.w);
    float w1 = shift_up1(a1), w2 = shift_up1(a2), w3 = shift_up1(a3);
    float w4 = a0, w5 = a1, w6 = a2, w7 = a3;
    // step 1 (time t): descending window update
    w7 = (w7 + w6 + kf7 * w5) * Pb.w;
    w6 = (w6 + w5) * Pb.z;
    w5 = (w5 + w4 + kf5 * w3) * Pb.y;
    w4 = (w4 + w3) * Pb.x;
    w3 = (w3 + w2 + kf3 * w1) * paw;
    w2 = (w2 + w1) * paz;
    // step 2 (time t+1): own states only
    w7 = (w7 + w6 + kf7 * w5) * Pc.w;
    w6 = (w6 + w5) * Pc.z;
    w5 = (w5 + w4 + kf5 * w3) * Pc.y;
    w4 = (w4 + w3) * Pc.x;
    a0 = w4; a1 = w5; a2 = w6; a3 = w7;

    if (e & 1) {          // renorm every 2 exchanges = 4 steps
      float mx = fmaxf(fmaxf(a0, a1), fmaxf(a2, a3));
      float Mx = wave_max64(mx);
      // rescale so max lands in [2^64, 2^65): exact power-of-2 scaling.
      int ee = ilogbf(fmaxf(Mx, 1.17549435e-38f)) - 64;
      float sc = ldexpf(1.0f, -ee);
      a0 *= sc; a1 *= sc; a2 *= sc; a3 *= sc;
      E += ee;
    }

    Pb = Nb; Pc = Nc;
  }
  // drain remaining in-flight LDS writes before reusing anything / ending.
  asm volatile("s_waitcnt vmcnt(0)" ::: "memory");

  // tail: at most one leftover single step (row read direct from global)
  int t = 1 + 2 * NE;
  if (t < Tb) {
    float4 P = pb4[(size_t)t * 64 + l];
    float u3 = shift_up1(a3);
    float n0 = (a0 + u3) * P.x;
    float n1 = (a1 + a0 + kf5 * u3) * P.y;
    float n2 = (a2 + a1) * P.z;
    float n3 = (a3 + a2 + kf7 * a1) * P.w;
    a0 = n0; a1 = n1; a2 = n2; a3 = n3;
  }

  sA[4 * l + 0] = a0; sA[4 * l + 1] = a1;
  sA[4 * l + 2] = a2; sA[4 * l + 3] = a3;
  __syncthreads();
  if (l == 0) {
    double ab = (double)sA[2 * Lb];       // final blank state
    double al_ = (double)sA[2 * Lb - 1];  // final label state
    costs[b] = -(log(ab + al_) + (double)E * 0.6931471805599453);
  }
}

__global__ __launch_bounds__(64) void k_final(
    const double* __restrict__ costs, const int* __restrict__ tlen,
    float* __restrict__ out, int B)
{
  int i = threadIdx.x;
  double c = (i < B) ? costs[i] : 0.0;
  double tl = (i < B) ? (double)tlen[i] : 0.0;
  #pragma unroll
  for (int o = 32; o > 0; o >>= 1) {
    c += __shfl_xor(c, o);
    tl += __shfl_xor(tl, o);
  }
  if (i == 0) out[0] = (float)(c / (double)B / tl);
}

extern "C" void kernel_launch(void* const* d_in, const int* in_sizes, int n_in,
                              void* d_out, int out_size, void* d_ws, size_t ws_size,
                              hipStream_t stream) {
  const float* act     = (const float*)d_in[0];   // [T,B,C] fp32
  const int*   targets = (const int*)d_in[1];     // [B*L]
  const int*   ilen    = (const int*)d_in[2];     // [B]
  const int*   tlen    = (const int*)d_in[3];     // [B]
  float* out = (float*)d_out;

  int B = in_sizes[2];
  int L = in_sizes[1] / B;
  const int T = 1000, C = 2000;     // fixed by the problem (in_sizes[0] = T*B*C)
  int S = 2 * L + 1;                // 201 <= 256

  float* p_ext = (float*)d_ws;                           // B*T*256 floats (~32.8 MB)
  double* costs = (double*)(p_ext + (size_t)B * T * 256); // B doubles (8B-aligned)

  k_lse_gather<<<T * B, BLK, 0, stream>>>(act, targets, p_ext, T, B, C, L, S);
  k_alpha<<<B, 64, 0, stream>>>(p_ext, targets, ilen, tlen, costs, T, B, L);
  k_final<<<1, 64, 0, stream>>>(costs, tlen, out, B);
}

// Round 4
// 440.537 us; speedup vs baseline: 1.2206x; 1.0817x over previous
//
#include <hip/hip_runtime.h>
#include <math.h>

// CTC loss (warp-ctc 'mean' reduction) on MI355X.
// Phase 1: per-(t,b) log-softmax denom + gather extended-label probs.
//          One WAVE per (t,b) row (4 rows per 256-thread block): 8 dwordx4
//          in flight per lane, pure-DPP reductions, no __syncthreads.
// Phase 2: linear-space alpha recursion, 1 wave/utterance, 4 states/lane,
//          2 DP steps per exchange. Memory via chunked DOUBLE-BUFFER:
//          2 x 32-row (32KB) LDS buffers, one vmcnt(0) per 16 exchanges,
//          issued a full chunk ahead (~2200 cy cover) — robust even if the
//          compiler inserts its own waits (round-3 ring serialized at
//          ~650 cy/exchange; this bounds worst case at ~+40 cy/exchange).
// Phase 3: double-precision reduction to the scalar.

#define BLK 256
#define CH 32      // rows per chunk = 16 exchanges; 2 x 32KB LDS buffers

typedef float f32x4 __attribute__((ext_vector_type(4)));

// ---------------- DPP wave helpers ----------------
// 64-lane max reduction; returns uniform value (all inputs >= 0).
__device__ __forceinline__ float wave_max64(float x) {
  int t;
  t = __builtin_amdgcn_update_dpp(0, __float_as_int(x), 0x111, 0xF, 0xF, true);  // row_shr:1
  x = fmaxf(x, __int_as_float(t));
  t = __builtin_amdgcn_update_dpp(0, __float_as_int(x), 0x112, 0xF, 0xF, true);  // row_shr:2
  x = fmaxf(x, __int_as_float(t));
  t = __builtin_amdgcn_update_dpp(0, __float_as_int(x), 0x114, 0xF, 0xF, true);  // row_shr:4
  x = fmaxf(x, __int_as_float(t));
  t = __builtin_amdgcn_update_dpp(0, __float_as_int(x), 0x118, 0xF, 0xF, true);  // row_shr:8
  x = fmaxf(x, __int_as_float(t));
  t = __builtin_amdgcn_update_dpp(0, __float_as_int(x), 0x142, 0xA, 0xF, false); // row_bcast:15
  x = fmaxf(x, __int_as_float(t));
  t = __builtin_amdgcn_update_dpp(0, __float_as_int(x), 0x143, 0xC, 0xF, false); // row_bcast:31
  x = fmaxf(x, __int_as_float(t));
  return __int_as_float(__builtin_amdgcn_readlane(__float_as_int(x), 63));
}

// 64-lane sum reduction, same DPP ladder (identity 0 = bound_ctrl fill).
__device__ __forceinline__ float wave_sum64(float x) {
  int t;
  t = __builtin_amdgcn_update_dpp(0, __float_as_int(x), 0x111, 0xF, 0xF, true);
  x += __int_as_float(t);
  t = __builtin_amdgcn_update_dpp(0, __float_as_int(x), 0x112, 0xF, 0xF, true);
  x += __int_as_float(t);
  t = __builtin_amdgcn_update_dpp(0, __float_as_int(x), 0x114, 0xF, 0xF, true);
  x += __int_as_float(t);
  t = __builtin_amdgcn_update_dpp(0, __float_as_int(x), 0x118, 0xF, 0xF, true);
  x += __int_as_float(t);
  t = __builtin_amdgcn_update_dpp(0, __float_as_int(x), 0x142, 0xA, 0xF, false);
  x += __int_as_float(t);
  t = __builtin_amdgcn_update_dpp(0, __float_as_int(x), 0x143, 0xC, 0xF, false);
  x += __int_as_float(t);
  return __int_as_float(__builtin_amdgcn_readlane(__float_as_int(x), 63));
}

// lane i <- lane i-1, lane 0 <- 0. DPP wave_shr:1 with bound_ctrl zero-fill.
__device__ __forceinline__ float shift_up1(float x) {
  int t = __builtin_amdgcn_update_dpp(0, __float_as_int(x), 0x138, 0xF, 0xF, true);
  return __int_as_float(t);
}

// async global -> LDS, 16 B per lane. LDS dest = uniform base + lane*16.
__device__ __forceinline__ void gload_lds16(const float* g, float* l) {
  __builtin_amdgcn_global_load_lds(
      (const __attribute__((address_space(1))) void*)(const void*)g,
      (__attribute__((address_space(3))) void*)(void*)l, 16, 0, 0);
}

// ---------------- Phase 1: wave-per-row LSE + gather ----------------
__global__ __launch_bounds__(BLK) void k_lse_gather(
    const float* __restrict__ act, const int* __restrict__ targets,
    float* __restrict__ p_ext, int T, int B, int C, int L, int S)
{
  int l = threadIdx.x & 63;
  int row = blockIdx.x * 4 + (threadIdx.x >> 6);  // one wave per (t,b) row
  if (row >= T * B) return;                        // wave-uniform exit
  int b = row % B;
  int t = row / B;
  const float* rp = act + (size_t)row * (size_t)C;
  const float4* rp4 = (const float4*)rp;
  int C4 = C >> 2;                 // 500 for C=2000

  // 8 float4 per lane, all issued up front (128 B/lane in flight).
  const float4 PAD = make_float4(-3e38f, -3e38f, -3e38f, -3e38f);
  float4 x0 = rp4[l];
  float4 x1 = rp4[l + 64];
  float4 x2 = rp4[l + 128];
  float4 x3 = rp4[l + 192];
  float4 x4 = rp4[l + 256];
  float4 x5 = rp4[l + 320];
  float4 x6 = rp4[l + 384];
  float4 x7 = (l + 448 < C4) ? rp4[l + 448] : PAD;   // only tail chunk ragged

  float m = fmaxf(fmaxf(x0.x, x0.y), fmaxf(x0.z, x0.w));
  m = fmaxf(m, fmaxf(fmaxf(x1.x, x1.y), fmaxf(x1.z, x1.w)));
  m = fmaxf(m, fmaxf(fmaxf(x2.x, x2.y), fmaxf(x2.z, x2.w)));
  m = fmaxf(m, fmaxf(fmaxf(x3.x, x3.y), fmaxf(x3.z, x3.w)));
  m = fmaxf(m, fmaxf(fmaxf(x4.x, x4.y), fmaxf(x4.z, x4.w)));
  m = fmaxf(m, fmaxf(fmaxf(x5.x, x5.y), fmaxf(x5.z, x5.w)));
  m = fmaxf(m, fmaxf(fmaxf(x6.x, x6.y), fmaxf(x6.z, x6.w)));
  m = fmaxf(m, fmaxf(fmaxf(x7.x, x7.y), fmaxf(x7.z, x7.w)));
  float M = wave_max64(m);

  float s = 0.f;
  s += expf(x0.x - M) + expf(x0.y - M) + expf(x0.z - M) + expf(x0.w - M);
  s += expf(x1.x - M) + expf(x1.y - M) + expf(x1.z - M) + expf(x1.w - M);
  s += expf(x2.x - M) + expf(x2.y - M) + expf(x2.z - M) + expf(x2.w - M);
  s += expf(x3.x - M) + expf(x3.y - M) + expf(x3.z - M) + expf(x3.w - M);
  s += expf(x4.x - M) + expf(x4.y - M) + expf(x4.z - M) + expf(x4.w - M);
  s += expf(x5.x - M) + expf(x5.y - M) + expf(x5.z - M) + expf(x5.w - M);
  s += expf(x6.x - M) + expf(x6.y - M) + expf(x6.z - M) + expf(x6.w - M);
  s += expf(x7.x - M) + expf(x7.y - M) + expf(x7.z - M) + expf(x7.w - M); // pads -> 0
  float Ssum = wave_sum64(s);
  float lse = M + logf(Ssum);

  // gather; pad slots [S,256) with 0 so invalid DP states stay exactly 0.
  const int* tg = targets + b * L;
  float* op = p_ext + ((size_t)b * T + t) * 256;
  #pragma unroll
  for (int q = 0; q < 4; ++q) {
    int sidx = l + 64 * q;
    float p = 0.f;
    if (sidx < S) {
      int c = (sidx & 1) ? tg[sidx >> 1] : 0;   // blank == 0
      p = expf(rp[c] - lse);
    }
    op[sidx] = p;
  }
}

// ---------------- Phase 2: alpha recursion, chunked double-buffer ----------------
__global__ __launch_bounds__(64, 1) void k_alpha(
    const float* __restrict__ p_ext, const int* __restrict__ targets,
    const int* __restrict__ ilen, const int* __restrict__ tlen,
    double* __restrict__ costs, int T, int B, int L)
{
  __shared__ float buf[2][CH * 256];   // 2 x 32 KB
  __shared__ float sA[260];

  int b = blockIdx.x;
  int l = threadIdx.x;              // lane owns states 4l..4l+3
  int Tb = ilen[b];
  int Lb = tlen[b];
  int S = 2 * Lb + 1;

  const float* pbase = p_ext + (size_t)b * (size_t)T * 256;
  const float4* pb4 = (const float4*)pbase;
  int tmax = T - 1;                 // uniform row clamp; clamped rows unused

  // skip flags (0/1 floats) for the odd states this lane updates:
  // kf3 -> state 4l-1 (halo recompute), kf5 -> 4l+1, kf7 -> 4l+3.
  const int* tg = targets + b * L;
  float kf3 = 0.f, kf5 = 0.f, kf7 = 0.f;
  {
    int s;
    s = 4 * l - 1; if (s >= 3 && s < S) { int mm = (s - 1) >> 1; kf3 = (tg[mm] != tg[mm - 1]) ? 1.f : 0.f; }
    s = 4 * l + 1; if (s >= 3 && s < S) { int mm = (s - 1) >> 1; kf5 = (tg[mm] != tg[mm - 1]) ? 1.f : 0.f; }
    s = 4 * l + 3; if (s >= 3 && s < S) { int mm = (s - 1) >> 1; kf7 = (tg[mm] != tg[mm - 1]) ? 1.f : 0.f; }
  }

  // t = 0 init, pre-biased to 2^64 (true alpha = stored * 2^E).
  const float BIAS = 18446744073709551616.0f;   // 2^64
  float a0 = 0.f, a1 = 0.f, a2 = 0.f, a3 = 0.f;
  {
    float4 p0 = pb4[l];
    if (l == 0) { a0 = p0.x * BIAS; a1 = p0.y * BIAS; }
  }
  int E = -64;

  int NE = (Tb - 1) >> 1;           // full 2-step exchanges
  int NCH = (NE + 15) >> 4;         // chunks of 16 exchanges

  // chunk k covers global rows 1+32k .. 32+32k (clamped).
  #define ISSUE_CHUNK(KK, DST) do {                                          \
      int _k = (KK);                                                         \
      _Pragma("unroll")                                                      \
      for (int _r = 0; _r < CH; ++_r) {                                      \
        int _t = 1 + CH * _k + _r; if (_t > tmax) _t = tmax;                 \
        gload_lds16(pbase + (size_t)_t * 256 + 4 * l, (DST) + _r * 256);     \
      }                                                                      \
    } while (0)

  // prologue: chunk 0 -> buf[0], drain, chunk 1 -> buf[1], read exchange 0.
  ISSUE_CHUNK(0, buf[0]);
  asm volatile("s_waitcnt vmcnt(0)" ::: "memory");
  ISSUE_CHUNK(1, buf[1]);
  f32x4 Pb = *(const f32x4*)&buf[0][0 * 256 + 4 * l];
  f32x4 Pc = *(const f32x4*)&buf[0][1 * 256 + 4 * l];

  int e = 0;
  for (int k = 0; k < NCH; ++k) {
    float* cur = buf[k & 1];
    float* nxt = buf[(k + 1) & 1];
    #pragma unroll
    for (int j = 0; j < 16; ++j) {
      // prefetch next exchange's rows (compile-time LDS offsets)
      f32x4 Nb, Nc;
      if (j < 15) {
        Nb = *(const f32x4*)&cur[(2 * j + 2) * 256 + 4 * l];
        Nc = *(const f32x4*)&cur[(2 * j + 3) * 256 + 4 * l];
      } else {
        // chunk k+1 was issued a full chunk ago (~2200 cy): drain is ~free.
        asm volatile("s_waitcnt vmcnt(0)" ::: "memory");
        ISSUE_CHUNK(k + 2, cur);          // cur is free: Pb/Pc in regs
        Nb = *(const f32x4*)&nxt[0 * 256 + 4 * l];
        Nc = *(const f32x4*)&nxt[1 * 256 + 4 * l];
      }

      if (e < NE) {                       // wave-uniform guard
        // halo row values = prev lane's Pb.z/.w (DPP wave_shr:1, lane0 -> 0)
        float paz = shift_up1(Pb.z), paw = shift_up1(Pb.w);
        float w1 = shift_up1(a1), w2 = shift_up1(a2), w3 = shift_up1(a3);
        float w4 = a0, w5 = a1, w6 = a2, w7 = a3;
        // step 1 (time t): descending window update
        w7 = (w7 + w6 + kf7 * w5) * Pb.w;
        w6 = (w6 + w5) * Pb.z;
        w5 = (w5 + w4 + kf5 * w3) * Pb.y;
        w4 = (w4 + w3) * Pb.x;
        w3 = (w3 + w2 + kf3 * w1) * paw;
        w2 = (w2 + w1) * paz;
        // step 2 (time t+1): own states only
        w7 = (w7 + w6 + kf7 * w5) * Pc.w;
        w6 = (w6 + w5) * Pc.z;
        w5 = (w5 + w4 + kf5 * w3) * Pc.y;
        w4 = (w4 + w3) * Pc.x;
        a0 = w4; a1 = w5; a2 = w6; a3 = w7;

        if (e & 1) {          // renorm every 2 exchanges = 4 steps
          float mx = fmaxf(fmaxf(a0, a1), fmaxf(a2, a3));
          float Mx = wave_max64(mx);
          float Mc = fmaxf(Mx, 1.17549435e-38f);
          // exact power-of-2 rescale via exponent bit ops (no libm):
          int ee = (int)((__float_as_uint(Mc) >> 23) & 0xFFu) - 127 - 64;
          float sc = __uint_as_float((unsigned)(127 - ee) << 23);
          a0 *= sc; a1 *= sc; a2 *= sc; a3 *= sc;
          E += ee;
        }
      }
      Pb = Nb; Pc = Nc; ++e;
    }
  }
  // drain any still-in-flight chunk loads before kernel teardown.
  asm volatile("s_waitcnt vmcnt(0)" ::: "memory");

  // tail: at most one leftover single step (row read direct from global)
  int t = 1 + 2 * NE;
  if (t < Tb) {
    float4 P = pb4[(size_t)t * 64 + l];
    float u3 = shift_up1(a3);
    float n0 = (a0 + u3) * P.x;
    float n1 = (a1 + a0 + kf5 * u3) * P.y;
    float n2 = (a2 + a1) * P.z;
    float n3 = (a3 + a2 + kf7 * a1) * P.w;
    a0 = n0; a1 = n1; a2 = n2; a3 = n3;
  }

  sA[4 * l + 0] = a0; sA[4 * l + 1] = a1;
  sA[4 * l + 2] = a2; sA[4 * l + 3] = a3;
  __syncthreads();
  if (l == 0) {
    double ab = (double)sA[2 * Lb];       // final blank state
    double al_ = (double)sA[2 * Lb - 1];  // final label state
    costs[b] = -(log(ab + al_) + (double)E * 0.6931471805599453);
  }
}

__global__ __launch_bounds__(64) void k_final(
    const double* __restrict__ costs, const int* __restrict__ tlen,
    float* __restrict__ out, int B)
{
  int i = threadIdx.x;
  double c = (i < B) ? costs[i] : 0.0;
  double tl = (i < B) ? (double)tlen[i] : 0.0;
  #pragma unroll
  for (int o = 32; o > 0; o >>= 1) {
    c += __shfl_xor(c, o);
    tl += __shfl_xor(tl, o);
  }
  if (i == 0) out[0] = (float)(c / (double)B / tl);
}

extern "C" void kernel_launch(void* const* d_in, const int* in_sizes, int n_in,
                              void* d_out, int out_size, void* d_ws, size_t ws_size,
                              hipStream_t stream) {
  const float* act     = (const float*)d_in[0];   // [T,B,C] fp32
  const int*   targets = (const int*)d_in[1];     // [B*L]
  const int*   ilen    = (const int*)d_in[2];     // [B]
  const int*   tlen    = (const int*)d_in[3];     // [B]
  float* out = (float*)d_out;

  int B = in_sizes[2];
  int L = in_sizes[1] / B;
  const int T = 1000, C = 2000;     // fixed by the problem (in_sizes[0] = T*B*C)
  int S = 2 * L + 1;                // 201 <= 256

  float* p_ext = (float*)d_ws;                           // B*T*256 floats (~32.8 MB)
  double* costs = (double*)(p_ext + (size_t)B * T * 256); // B doubles (8B-aligned)

  int rows = T * B;
  k_lse_gather<<<(rows + 3) / 4, BLK, 0, stream>>>(act, targets, p_ext, T, B, C, L, S);
  k_alpha<<<B, 64, 0, stream>>>(p_ext, targets, ilen, tlen, costs, T, B, L);
  k_final<<<1, 64, 0, stream>>>(costs, tlen, out, B);
}